// Round 4
// baseline (921.169 us; speedup 1.0000x reference)
//
#include <hip/hip_runtime.h>
#include <math.h>

#define NB    200
#define DIMH  128
#define ROWS  4
#define TPB   256
#define NITER 22   // 50 in ref; tau err <= 0.411*2^-22 ~ 1e-7 -> p err ~1e-6, well under threshold

__device__ __forceinline__ float pow10_(float x){
    float x2 = x*x; float x4 = x2*x2; float x8 = x4*x4; return x8*x2;
}
__device__ __forceinline__ float rdlane(float v, int l){
    return __builtin_bit_cast(float,
        __builtin_amdgcn_readlane(__builtin_bit_cast(int, v), l));
}

// Wave64 reduce via DPP (row_shr 1/2/4/8 + row_bcast 15/31), uniform result.
__device__ __forceinline__ float wsum_dpp(float v){
#define DPP_ADD(ctrl, rmask)                                                     \
    {                                                                            \
        int t_ = __builtin_amdgcn_update_dpp(0, __builtin_bit_cast(int, v),      \
                                             ctrl, rmask, 0xf, false);           \
        v += __builtin_bit_cast(float, t_);                                      \
    }
    DPP_ADD(0x111, 0xf)
    DPP_ADD(0x112, 0xf)
    DPP_ADD(0x114, 0xf)
    DPP_ADD(0x118, 0xf)
    DPP_ADD(0x142, 0xa)
    DPP_ADD(0x143, 0xc)
#undef DPP_ADD
    return rdlane(v, 63);
}
__device__ __forceinline__ float wmax_dpp(float v){
#define DPP_MAX(ctrl, rmask)                                                     \
    {                                                                            \
        int t_ = __builtin_amdgcn_update_dpp(__builtin_bit_cast(int, v),         \
                                             __builtin_bit_cast(int, v),         \
                                             ctrl, rmask, 0xf, false);           \
        v = fmaxf(v, __builtin_bit_cast(float, t_));                             \
    }
    DPP_MAX(0x111, 0xf)
    DPP_MAX(0x112, 0xf)
    DPP_MAX(0x114, 0xf)
    DPP_MAX(0x118, 0xf)
    DPP_MAX(0x142, 0xa)
    DPP_MAX(0x143, 0xc)
#undef DPP_MAX
    return rdlane(v, 63);
}

__global__ __launch_bounds__(TPB, 8) void la_fused(
    const float* __restrict__ hidden,
    const int*   __restrict__ adj,
    const int*   __restrict__ mask,
    const float* __restrict__ a0, const float* __restrict__ a1,
    const float* __restrict__ a2, const float* __restrict__ a3,
    const float* __restrict__ W,  const float* __restrict__ bias,
    float* __restrict__ out)
{
    __shared__ float ha[ROWS][4][132];   // h_i[d]*a_k[d]; stride 132 keeps the 4 k-rows on distinct banks
    __shared__ float xs[ROWS][256];      // score handoff (column-owner threads -> row-owner waves)

    const int t    = threadIdx.x;
    const int lane = t & 63;
    const int r    = t >> 6;             // this wave's row
    const int bid  = blockIdx.x;
    const int b    = bid / (NB / ROWS);
    const int i0   = (bid % (NB / ROWS)) * ROWS;

    const float* hb = hidden + (size_t)b * NB * DIMH;
    const int d0 = 2 * lane;             // this lane's output dims: d0, d0+1

    // this wave's row of h, register-resident (lane j holds dims 2j, 2j+1)
    float2 hrow = *(const float2*)(hb + (i0 + r) * DIMH + d0);

    // ---- stage ha table ----
    for (int idx = t; idx < ROWS * 4 * DIMH; idx += TPB) {
        int rr = idx >> 9, k = (idx >> 7) & 3, d = idx & 127;
        float av = (k == 0) ? a0[d] : (k == 1) ? a1[d] : (k == 2) ? a2[d] : a3[d];
        ha[rr][k][d] = hb[(i0 + rr) * DIMH + d] * av;
    }
    __syncthreads();

    // ---- phase S: thread t owns column j=t for all 4 rows ----
    if (t < NB) {
        const int m = mask[b * NB + t];
        int kk[ROWS];
        #pragma unroll
        for (int rr = 0; rr < ROWS; rr++)
            kk[rr] = adj[((size_t)(b * NB + i0 + rr)) * NB + t];
        int ksel[ROWS];
        #pragma unroll
        for (int rr = 0; rr < ROWS; rr++) ksel[rr] = (kk[rr] > 0) ? (kk[rr] - 1) : 0;

        float acc[ROWS] = {0.f, 0.f, 0.f, 0.f};
        const float* hj = hb + t * DIMH;
        #pragma unroll 4
        for (int d = 0; d < DIMH; d += 4) {
            float4 hv = *(const float4*)(hj + d);
            #pragma unroll
            for (int rr = 0; rr < ROWS; rr++) {
                const float4 av4 = *(const float4*)&ha[rr][ksel[rr]][d];
                acc[rr] = fmaf(hv.x, av4.x, acc[rr]);
                acc[rr] = fmaf(hv.y, av4.y, acc[rr]);
                acc[rr] = fmaf(hv.z, av4.z, acc[rr]);
                acc[rr] = fmaf(hv.w, av4.w, acc[rr]);
            }
        }
        #pragma unroll
        for (int rr = 0; rr < ROWS; rr++) {
            float x;
            if (m == 0)           x = -INFINITY;           // mask fill
            else if (kk[rr] == 0) x = 0.0f;                // no edge: sel=0
            else {
                float e = acc[rr];
                e = (e >= 0.0f) ? e : 0.2f * e;            // leaky relu 0.2
                x = e * 0.1f;                              // * (alpha-1)
            }
            xs[rr][t] = x;
        }
    } else {
        #pragma unroll
        for (int rr = 0; rr < ROWS; rr++) xs[rr][t] = -INFINITY;  // pad
    }
    __syncthreads();

    // ---- entmax bisection: wave r owns row i0+r; p stays in registers ----
    float x0 = xs[r][lane];
    float x1 = xs[r][lane + 64];
    float x2 = xs[r][lane + 128];
    float x3 = xs[r][lane + 192];

    float mx  = wmax_dpp(fmaxf(fmaxf(x0, x1), fmaxf(x2, x3)));
    float tau = mx - 1.0f;
    float s0  = pow10_(fmaxf(x0 - tau, 0.f)) + pow10_(fmaxf(x1 - tau, 0.f))
              + pow10_(fmaxf(x2 - tau, 0.f)) + pow10_(fmaxf(x3 - tau, 0.f));
    float f_lo = wsum_dpp(s0) - 1.0f;              // captured once (matches ref closure)
    float dm   = (mx - 0.58870401f) - tau;         // tau_hi - tau_lo; (1/200)^0.1

    for (int itn = 0; itn < NITER; ++itn) {
        dm *= 0.5f;
        float tm = tau + dm;
        float s = pow10_(fmaxf(x0 - tm, 0.f)) + pow10_(fmaxf(x1 - tm, 0.f))
                + pow10_(fmaxf(x2 - tm, 0.f)) + pow10_(fmaxf(x3 - tm, 0.f));
        float fm = wsum_dpp(s) - 1.0f;
        if (fm * f_lo >= 0.0f) tau = tm;
    }
    float p0 = pow10_(fmaxf(x0 - tau, 0.f));
    float p1 = pow10_(fmaxf(x1 - tau, 0.f));
    float p2 = pow10_(fmaxf(x2 - tau, 0.f));
    float p3 = pow10_(fmaxf(x3 - tau, 0.f));
    float sinv = 1.0f / wsum_dpp(p0 + p1 + p2 + p3);   // ensure_sum_one
    float pn0 = p0 * sinv, pn1 = p1 * sinv, pn2 = p2 * sinv, pn3 = p3 * sinv;

    // ---- PV: o[d] = sum_j p[j]*h[b,j,d]; p broadcast via readlane (no LDS) ----
    const float* hbd = hb + d0;
    float o0 = 0.f, o1 = 0.f;
    #pragma unroll 4
    for (int j = 0; j < 64; ++j) {
        float pj = rdlane(pn0, j);
        float2 hv = *(const float2*)(hbd + j * DIMH);
        o0 = fmaf(pj, hv.x, o0); o1 = fmaf(pj, hv.y, o1);
    }
    #pragma unroll 4
    for (int j = 0; j < 64; ++j) {
        float pj = rdlane(pn1, j);
        float2 hv = *(const float2*)(hbd + (64 + j) * DIMH);
        o0 = fmaf(pj, hv.x, o0); o1 = fmaf(pj, hv.y, o1);
    }
    #pragma unroll 4
    for (int j = 0; j < 64; ++j) {
        float pj = rdlane(pn2, j);
        float2 hv = *(const float2*)(hbd + (128 + j) * DIMH);
        o0 = fmaf(pj, hv.x, o0); o1 = fmaf(pj, hv.y, o1);
    }
    #pragma unroll
    for (int j = 0; j < NB - 192; ++j) {           // cols 192..199
        float pj = rdlane(pn3, j);
        float2 hv = *(const float2*)(hbd + (192 + j) * DIMH);
        o0 = fmaf(pj, hv.x, o0); o1 = fmaf(pj, hv.y, o1);
    }

    // ---- gate: sigmoid([h_i, o] @ W + b); h/o broadcast via readlane ----
    float2 bv = *(const float2*)(bias + d0);
    float g0 = bv.x, g1 = bv.y;
    #pragma unroll 4
    for (int j = 0; j < 64; ++j) {                 // rows e=2j, 2j+1 of W (h part)
        float c0 = rdlane(hrow.x, j);
        float c1 = rdlane(hrow.y, j);
        float2 w0 = *(const float2*)(W + (2 * j) * DIMH + d0);
        float2 w1 = *(const float2*)(W + (2 * j + 1) * DIMH + d0);
        g0 = fmaf(c0, w0.x, g0); g1 = fmaf(c0, w0.y, g1);
        g0 = fmaf(c1, w1.x, g0); g1 = fmaf(c1, w1.y, g1);
    }
    #pragma unroll 4
    for (int j = 0; j < 64; ++j) {                 // rows e=128+2j, 128+2j+1 (o part)
        float c0 = rdlane(o0, j);
        float c1 = rdlane(o1, j);
        float2 w0 = *(const float2*)(W + (DIMH + 2 * j) * DIMH + d0);
        float2 w1 = *(const float2*)(W + (DIMH + 2 * j + 1) * DIMH + d0);
        g0 = fmaf(c0, w0.x, g0); g1 = fmaf(c0, w0.y, g1);
        g0 = fmaf(c1, w1.x, g0); g1 = fmaf(c1, w1.y, g1);
    }
    float sg0 = 1.0f / (1.0f + __expf(-g0));
    float sg1 = 1.0f / (1.0f + __expf(-g1));

    const size_t gi = (size_t)(b * NB + i0 + r) * DIMH;
    *(float2*)(out + gi + d0) =
        make_float2(sg0 * o0 + (1.0f - sg0) * hrow.x,
                    sg1 * o1 + (1.0f - sg1) * hrow.y);
}

extern "C" void kernel_launch(void* const* d_in, const int* in_sizes, int n_in,
                              void* d_out, int out_size, void* d_ws, size_t ws_size,
                              hipStream_t stream)
{
    const float* hidden = (const float*)d_in[0];
    const int*   adj    = (const int*)d_in[1];
    const int*   mask   = (const int*)d_in[2];
    const float* a0     = (const float*)d_in[3];
    const float* a1     = (const float*)d_in[4];
    const float* a2     = (const float*)d_in[5];
    const float* a3     = (const float*)d_in[6];
    const float* W      = (const float*)d_in[7];
    const float* bias   = (const float*)d_in[8];
    float* out = (float*)d_out;

    const int B = in_sizes[0] / (NB * DIMH);   // 256
    dim3 grid(B * (NB / ROWS));
    la_fused<<<grid, TPB, 0, stream>>>(hidden, adj, mask, a0, a1, a2, a3, W, bias, out);
}

// Round 5
// 853.399 us; speedup vs baseline: 1.0794x; 1.0794x over previous
//
#include <hip/hip_runtime.h>
#include <math.h>

#define NB    200
#define DIMH  128
#define ROWS  4
#define TPB   256
#define NITER 22   // 50 in ref; tau err <= 0.411*2^-22 ~ 1e-7 -> p err ~1e-6, well under threshold

__device__ __forceinline__ float pow10_(float x){
    float x2 = x*x; float x4 = x2*x2; float x8 = x4*x4; return x8*x2;
}
__device__ __forceinline__ float rdlane(float v, int l){
    return __builtin_bit_cast(float,
        __builtin_amdgcn_readlane(__builtin_bit_cast(int, v), l));
}

// Wave64 reduce via DPP (row_shr 1/2/4/8 + row_bcast 15/31), uniform result.
__device__ __forceinline__ float wsum_dpp(float v){
#define DPP_ADD(ctrl, rmask)                                                     \
    {                                                                            \
        int t_ = __builtin_amdgcn_update_dpp(0, __builtin_bit_cast(int, v),      \
                                             ctrl, rmask, 0xf, false);           \
        v += __builtin_bit_cast(float, t_);                                      \
    }
    DPP_ADD(0x111, 0xf)
    DPP_ADD(0x112, 0xf)
    DPP_ADD(0x114, 0xf)
    DPP_ADD(0x118, 0xf)
    DPP_ADD(0x142, 0xa)
    DPP_ADD(0x143, 0xc)
#undef DPP_ADD
    return rdlane(v, 63);
}
__device__ __forceinline__ float wmax_dpp(float v){
#define DPP_MAX(ctrl, rmask)                                                     \
    {                                                                            \
        int t_ = __builtin_amdgcn_update_dpp(__builtin_bit_cast(int, v),         \
                                             __builtin_bit_cast(int, v),         \
                                             ctrl, rmask, 0xf, false);           \
        v = fmaxf(v, __builtin_bit_cast(float, t_));                             \
    }
    DPP_MAX(0x111, 0xf)
    DPP_MAX(0x112, 0xf)
    DPP_MAX(0x114, 0xf)
    DPP_MAX(0x118, 0xf)
    DPP_MAX(0x142, 0xa)
    DPP_MAX(0x143, 0xc)
#undef DPP_MAX
    return rdlane(v, 63);
}

// launch_bounds(256,8) capped VGPRs at 32 -> scratch spills (WRITE_SIZE 267MB).
// (256,6) caps ~80 VGPRs: no spill, 6 waves/SIMD.
__global__ __launch_bounds__(TPB, 6) void la_fused(
    const float* __restrict__ hidden,
    const int*   __restrict__ adj,
    const int*   __restrict__ mask,
    const float* __restrict__ a0, const float* __restrict__ a1,
    const float* __restrict__ a2, const float* __restrict__ a3,
    const float* __restrict__ W,  const float* __restrict__ bias,
    float* __restrict__ out)
{
    __shared__ float ha[ROWS][4][132];   // h_i[d]*a_k[d]; k-rows land on distinct banks
    __shared__ float xs[ROWS][256];      // score handoff (column threads -> row waves)

    const int t    = threadIdx.x;
    const int lane = t & 63;
    const int r    = t >> 6;             // this wave's row
    const int bid  = blockIdx.x;
    const int b    = bid / (NB / ROWS);
    const int i0   = (bid % (NB / ROWS)) * ROWS;

    const float* hb = hidden + (size_t)b * NB * DIMH;
    const int d0 = 2 * lane;             // this lane's output dims: d0, d0+1

    // this wave's row of h, register-resident (lane j holds dims 2j, 2j+1)
    float2 hrow = *(const float2*)(hb + (i0 + r) * DIMH + d0);

    // ---- stage ha table ----
    for (int idx = t; idx < ROWS * 4 * DIMH; idx += TPB) {
        int rr = idx >> 9, k = (idx >> 7) & 3, d = idx & 127;
        float av = (k == 0) ? a0[d] : (k == 1) ? a1[d] : (k == 2) ? a2[d] : a3[d];
        ha[rr][k][d] = hb[(i0 + rr) * DIMH + d] * av;
    }
    __syncthreads();

    // ---- phase S: thread t owns column j=t for all 4 rows ----
    if (t < NB) {
        const int m = mask[b * NB + t];
        int kk[ROWS];
        #pragma unroll
        for (int rr = 0; rr < ROWS; rr++)
            kk[rr] = adj[((size_t)(b * NB + i0 + rr)) * NB + t];
        int ksel[ROWS];
        #pragma unroll
        for (int rr = 0; rr < ROWS; rr++) ksel[rr] = (kk[rr] > 0) ? (kk[rr] - 1) : 0;

        float acc[ROWS] = {0.f, 0.f, 0.f, 0.f};
        const float* hj = hb + t * DIMH;
        #pragma unroll 4
        for (int d = 0; d < DIMH; d += 4) {
            float4 hv = *(const float4*)(hj + d);
            #pragma unroll
            for (int rr = 0; rr < ROWS; rr++) {
                const float4 av4 = *(const float4*)&ha[rr][ksel[rr]][d];
                acc[rr] = fmaf(hv.x, av4.x, acc[rr]);
                acc[rr] = fmaf(hv.y, av4.y, acc[rr]);
                acc[rr] = fmaf(hv.z, av4.z, acc[rr]);
                acc[rr] = fmaf(hv.w, av4.w, acc[rr]);
            }
        }
        #pragma unroll
        for (int rr = 0; rr < ROWS; rr++) {
            float x;
            if (m == 0)           x = -INFINITY;           // mask fill
            else if (kk[rr] == 0) x = 0.0f;                // no edge: sel=0
            else {
                float e = acc[rr];
                e = (e >= 0.0f) ? e : 0.2f * e;            // leaky relu 0.2
                x = e * 0.1f;                              // * (alpha-1)
            }
            xs[rr][t] = x;
        }
    } else {
        #pragma unroll
        for (int rr = 0; rr < ROWS; rr++) xs[rr][t] = -INFINITY;  // pad
    }
    __syncthreads();

    // ---- entmax bisection: wave r owns row i0+r; p stays in registers ----
    float x0 = xs[r][lane];
    float x1 = xs[r][lane + 64];
    float x2 = xs[r][lane + 128];
    float x3 = xs[r][lane + 192];

    float mx  = wmax_dpp(fmaxf(fmaxf(x0, x1), fmaxf(x2, x3)));
    float tau = mx - 1.0f;
    float s0  = pow10_(fmaxf(x0 - tau, 0.f)) + pow10_(fmaxf(x1 - tau, 0.f))
              + pow10_(fmaxf(x2 - tau, 0.f)) + pow10_(fmaxf(x3 - tau, 0.f));
    float f_lo = wsum_dpp(s0) - 1.0f;              // captured once (matches ref closure)
    float dm   = (mx - 0.58870401f) - tau;         // tau_hi - tau_lo; (1/200)^0.1

    for (int itn = 0; itn < NITER; ++itn) {
        dm *= 0.5f;
        float tm = tau + dm;
        float s = pow10_(fmaxf(x0 - tm, 0.f)) + pow10_(fmaxf(x1 - tm, 0.f))
                + pow10_(fmaxf(x2 - tm, 0.f)) + pow10_(fmaxf(x3 - tm, 0.f));
        float fm = wsum_dpp(s) - 1.0f;
        if (fm * f_lo >= 0.0f) tau = tm;
    }
    float p0 = pow10_(fmaxf(x0 - tau, 0.f));
    float p1 = pow10_(fmaxf(x1 - tau, 0.f));
    float p2 = pow10_(fmaxf(x2 - tau, 0.f));
    float p3 = pow10_(fmaxf(x3 - tau, 0.f));
    float sinv = 1.0f / wsum_dpp(p0 + p1 + p2 + p3);   // ensure_sum_one
    float pn0 = p0 * sinv, pn1 = p1 * sinv, pn2 = p2 * sinv, pn3 = p3 * sinv;

    // ---- PV: o[d] = sum_j p[j]*h[b,j,d]; p broadcast via readlane (no LDS) ----
    const float* hbd = hb + d0;
    float o0 = 0.f, o1 = 0.f;
    #pragma unroll 4
    for (int j = 0; j < 64; ++j) {
        float pj = rdlane(pn0, j);
        float2 hv = *(const float2*)(hbd + j * DIMH);
        o0 = fmaf(pj, hv.x, o0); o1 = fmaf(pj, hv.y, o1);
    }
    #pragma unroll 4
    for (int j = 0; j < 64; ++j) {
        float pj = rdlane(pn1, j);
        float2 hv = *(const float2*)(hbd + (64 + j) * DIMH);
        o0 = fmaf(pj, hv.x, o0); o1 = fmaf(pj, hv.y, o1);
    }
    #pragma unroll 4
    for (int j = 0; j < 64; ++j) {
        float pj = rdlane(pn2, j);
        float2 hv = *(const float2*)(hbd + (128 + j) * DIMH);
        o0 = fmaf(pj, hv.x, o0); o1 = fmaf(pj, hv.y, o1);
    }
    #pragma unroll
    for (int j = 0; j < NB - 192; ++j) {           // cols 192..199
        float pj = rdlane(pn3, j);
        float2 hv = *(const float2*)(hbd + (192 + j) * DIMH);
        o0 = fmaf(pj, hv.x, o0); o1 = fmaf(pj, hv.y, o1);
    }

    // ---- gate: sigmoid([h_i, o] @ W + b); h/o broadcast via readlane ----
    float2 bv = *(const float2*)(bias + d0);
    float g0 = bv.x, g1 = bv.y;
    #pragma unroll 4
    for (int j = 0; j < 64; ++j) {                 // rows e=2j, 2j+1 of W (h part)
        float c0 = rdlane(hrow.x, j);
        float c1 = rdlane(hrow.y, j);
        float2 w0 = *(const float2*)(W + (2 * j) * DIMH + d0);
        float2 w1 = *(const float2*)(W + (2 * j + 1) * DIMH + d0);
        g0 = fmaf(c0, w0.x, g0); g1 = fmaf(c0, w0.y, g1);
        g0 = fmaf(c1, w1.x, g0); g1 = fmaf(c1, w1.y, g1);
    }
    #pragma unroll 4
    for (int j = 0; j < 64; ++j) {                 // rows e=128+2j, 128+2j+1 (o part)
        float c0 = rdlane(o0, j);
        float c1 = rdlane(o1, j);
        float2 w0 = *(const float2*)(W + (DIMH + 2 * j) * DIMH + d0);
        float2 w1 = *(const float2*)(W + (DIMH + 2 * j + 1) * DIMH + d0);
        g0 = fmaf(c0, w0.x, g0); g1 = fmaf(c0, w0.y, g1);
        g0 = fmaf(c1, w1.x, g0); g1 = fmaf(c1, w1.y, g1);
    }
    float sg0 = 1.0f / (1.0f + __expf(-g0));
    float sg1 = 1.0f / (1.0f + __expf(-g1));

    const size_t gi = (size_t)(b * NB + i0 + r) * DIMH;
    *(float2*)(out + gi + d0) =
        make_float2(sg0 * o0 + (1.0f - sg0) * hrow.x,
                    sg1 * o1 + (1.0f - sg1) * hrow.y);
}

extern "C" void kernel_launch(void* const* d_in, const int* in_sizes, int n_in,
                              void* d_out, int out_size, void* d_ws, size_t ws_size,
                              hipStream_t stream)
{
    const float* hidden = (const float*)d_in[0];
    const int*   adj    = (const int*)d_in[1];
    const int*   mask   = (const int*)d_in[2];
    const float* a0     = (const float*)d_in[3];
    const float* a1     = (const float*)d_in[4];
    const float* a2     = (const float*)d_in[5];
    const float* a3     = (const float*)d_in[6];
    const float* W      = (const float*)d_in[7];
    const float* bias   = (const float*)d_in[8];
    float* out = (float*)d_out;

    const int B = in_sizes[0] / (NB * DIMH);   // 256
    dim3 grid(B * (NB / ROWS));
    la_fused<<<grid, TPB, 0, stream>>>(hidden, adj, mask, a0, a1, a2, a3, W, bias, out);
}

// Round 6
// 392.977 us; speedup vs baseline: 2.3441x; 2.1716x over previous
//
#include <hip/hip_runtime.h>
#include <math.h>

#define NB    200
#define DIMH  128
#define ROWS  4
#define TPB   256
#define NITER 22   // 50 in ref; tau err <= 0.411*2^-22 ~ 1e-7 -> p err ~1e-6, far under threshold

__device__ __forceinline__ float pow10_(float x){
    float x2 = x*x; float x4 = x2*x2; float x8 = x4*x4; return x8*x2;
}
__device__ __forceinline__ float rdlane(float v, int l){
    return __builtin_bit_cast(float,
        __builtin_amdgcn_readlane(__builtin_bit_cast(int, v), l));
}
// Wave64 reduce via DPP (row_shr 1/2/4/8 + row_bcast 15/31), uniform result.
__device__ __forceinline__ float wsum_dpp(float v){
#define DPP_ADD(ctrl, rmask)                                                     \
    {                                                                            \
        int t_ = __builtin_amdgcn_update_dpp(0, __builtin_bit_cast(int, v),      \
                                             ctrl, rmask, 0xf, false);           \
        v += __builtin_bit_cast(float, t_);                                      \
    }
    DPP_ADD(0x111, 0xf)
    DPP_ADD(0x112, 0xf)
    DPP_ADD(0x114, 0xf)
    DPP_ADD(0x118, 0xf)
    DPP_ADD(0x142, 0xa)
    DPP_ADD(0x143, 0xc)
#undef DPP_ADD
    return rdlane(v, 63);
}
__device__ __forceinline__ float wmax_dpp(float v){
#define DPP_MAX(ctrl, rmask)                                                     \
    {                                                                            \
        int t_ = __builtin_amdgcn_update_dpp(__builtin_bit_cast(int, v),         \
                                             __builtin_bit_cast(int, v),         \
                                             ctrl, rmask, 0xf, false);           \
        v = fmaxf(v, __builtin_bit_cast(float, t_));                             \
    }
    DPP_MAX(0x111, 0xf)
    DPP_MAX(0x112, 0xf)
    DPP_MAX(0x114, 0xf)
    DPP_MAX(0x118, 0xf)
    DPP_MAX(0x142, 0xa)
    DPP_MAX(0x143, 0xc)
#undef DPP_MAX
    return rdlane(v, 63);
}

// (256,4) is the only empirically spill-free config on this kernel (r2/r3:
// WRITE_SIZE exactly 25.6MB; r1/r4/r5 all showed scratch traffic).
__global__ __launch_bounds__(TPB, 4) void la_fused(
    const float* __restrict__ hidden,
    const int*   __restrict__ adj,
    const int*   __restrict__ mask,
    const float* __restrict__ a0, const float* __restrict__ a1,
    const float* __restrict__ a2, const float* __restrict__ a3,
    const float* __restrict__ W,  const float* __restrict__ bias,
    float* __restrict__ out)
{
    __shared__ float ha[ROWS][4][132];   // h_i[d]*a_k[d]; stride 132 -> k-rows on disjoint banks
    __shared__ float xs[ROWS][256];      // scores, then normalized p
    __shared__ float hi_s[ROWS][132];    // h_i rows (gate c-operand + final mix)
    __shared__ float ov_s[ROWS][132];    // o rows   (gate c-operand)
    __shared__ float wt[2][16][132];     // W chunk: [h-part/o-part][16 rows][128+pad]

    const int t    = threadIdx.x;
    const int lane = t & 63;
    const int r    = t >> 6;             // this wave's row
    const int half = lane >> 5;          // 0: j<100 / h-part; 1: j>=100 / o-part
    const int li   = lane & 31;
    const int d4   = 4 * li;             // this lane's 4 dims
    const int bid  = blockIdx.x;
    const int b    = bid / (NB / ROWS);
    const int i0   = (bid % (NB / ROWS)) * ROWS;

    const float* hb = hidden + (size_t)b * NB * DIMH;

    // ---- stage h_i rows and ha table ----
    for (int idx = t; idx < ROWS * DIMH; idx += TPB) {
        int rr = idx >> 7, d = idx & 127;
        hi_s[rr][d] = hb[(i0 + rr) * DIMH + d];
    }
    for (int idx = t; idx < ROWS * 4 * DIMH; idx += TPB) {
        int rr = idx >> 9, k = (idx >> 7) & 3, d = idx & 127;
        float av = (k == 0) ? a0[d] : (k == 1) ? a1[d] : (k == 2) ? a2[d] : a3[d];
        ha[rr][k][d] = hb[(i0 + rr) * DIMH + d] * av;
    }
    __syncthreads();

    // ---- phase S: thread t owns column j=t for all 4 rows ----
    if (t < NB) {
        const int m = mask[b * NB + t];
        int kk[ROWS];
        #pragma unroll
        for (int rr = 0; rr < ROWS; rr++)
            kk[rr] = adj[((size_t)(b * NB + i0 + rr)) * NB + t];
        int ksel[ROWS];
        #pragma unroll
        for (int rr = 0; rr < ROWS; rr++) ksel[rr] = (kk[rr] > 0) ? (kk[rr] - 1) : 0;

        float acc[ROWS] = {0.f, 0.f, 0.f, 0.f};
        const float* hj = hb + t * DIMH;
        #pragma unroll 4
        for (int d = 0; d < DIMH; d += 4) {
            float4 hv = *(const float4*)(hj + d);
            #pragma unroll
            for (int rr = 0; rr < ROWS; rr++) {
                const float4 av4 = *(const float4*)&ha[rr][ksel[rr]][d];
                acc[rr] = fmaf(hv.x, av4.x, acc[rr]);
                acc[rr] = fmaf(hv.y, av4.y, acc[rr]);
                acc[rr] = fmaf(hv.z, av4.z, acc[rr]);
                acc[rr] = fmaf(hv.w, av4.w, acc[rr]);
            }
        }
        #pragma unroll
        for (int rr = 0; rr < ROWS; rr++) {
            float x;
            if (m == 0)           x = -INFINITY;           // mask fill
            else if (kk[rr] == 0) x = 0.0f;                // no edge: sel=0
            else {
                float e = acc[rr];
                e = (e >= 0.0f) ? e : 0.2f * e;            // leaky relu 0.2
                x = e * 0.1f;                              // * (alpha-1)
            }
            xs[rr][t] = x;
        }
    } else {
        #pragma unroll
        for (int rr = 0; rr < ROWS; rr++) xs[rr][t] = -INFINITY;  // pad
    }
    __syncthreads();

    // ---- entmax bisection: wave r owns row i0+r ----
    float x0 = xs[r][lane];
    float x1 = xs[r][lane + 64];
    float x2 = xs[r][lane + 128];
    float x3 = xs[r][lane + 192];

    float mx  = wmax_dpp(fmaxf(fmaxf(x0, x1), fmaxf(x2, x3)));
    float tau = mx - 1.0f;
    float s0  = pow10_(fmaxf(x0 - tau, 0.f)) + pow10_(fmaxf(x1 - tau, 0.f))
              + pow10_(fmaxf(x2 - tau, 0.f)) + pow10_(fmaxf(x3 - tau, 0.f));
    float f_lo = wsum_dpp(s0) - 1.0f;              // captured once (matches ref closure)
    float dm   = (mx - 0.58870401f) - tau;         // tau_hi - tau_lo; (1/200)^0.1

    for (int itn = 0; itn < NITER; ++itn) {
        dm *= 0.5f;
        float tm = tau + dm;
        float s = pow10_(fmaxf(x0 - tm, 0.f)) + pow10_(fmaxf(x1 - tm, 0.f))
                + pow10_(fmaxf(x2 - tm, 0.f)) + pow10_(fmaxf(x3 - tm, 0.f));
        float fm = wsum_dpp(s) - 1.0f;
        if (fm * f_lo >= 0.0f) tau = tm;
    }
    float p0 = pow10_(fmaxf(x0 - tau, 0.f));
    float p1 = pow10_(fmaxf(x1 - tau, 0.f));
    float p2 = pow10_(fmaxf(x2 - tau, 0.f));
    float p3 = pow10_(fmaxf(x3 - tau, 0.f));
    float sinv = 1.0f / wsum_dpp(p0 + p1 + p2 + p3);   // ensure_sum_one
    // write normalized p back (wave-local; j>=200 slots hold 0, never read)
    xs[r][lane]       = p0 * sinv;
    xs[r][lane + 64]  = p1 * sinv;
    xs[r][lane + 128] = p2 * sinv;
    xs[r][lane + 192] = p3 * sinv;

    // ---- PV, half-split float4: half h covers j in [100h,100h+100), dims d4..d4+3 ----
    float4 o = make_float4(0.f, 0.f, 0.f, 0.f);
    {
        const float* hbase = hb + half * 100 * DIMH + d4;
        const float* xrow  = &xs[r][half * 100];
        #pragma unroll 4
        for (int jj = 0; jj < 100; ++jj) {
            float pj = xrow[jj];                       // 2-addr LDS broadcast (free)
            float4 hv = *(const float4*)(hbase + jj * DIMH);
            o.x = fmaf(pj, hv.x, o.x);
            o.y = fmaf(pj, hv.y, o.y);
            o.z = fmaf(pj, hv.z, o.z);
            o.w = fmaf(pj, hv.w, o.w);
        }
    }
    o.x += __shfl_xor(o.x, 32);                        // combine the two j-halves
    o.y += __shfl_xor(o.y, 32);
    o.z += __shfl_xor(o.z, 32);
    o.w += __shfl_xor(o.w, 32);
    if (half == 0) *(float4*)&ov_s[r][d4] = o;         // wave-local publish for gate c-reads

    // ---- gate: g[d] = sum_e c[e] W[e][d]; half 0: c=h_i, rows 0..127; half 1: c=o, rows 128..255
    float4 g = make_float4(0.f, 0.f, 0.f, 0.f);
    const float* cbase = half ? &ov_s[r][0] : &hi_s[r][0];
    for (int c = 0; c < 8; ++c) {
        __syncthreads();                                // previous chunk fully consumed
        #pragma unroll
        for (int q = 0; q < 4; ++q) {                   // stage 2x16 W rows, coalesced
            int fidx = q * TPB + t;                     // 0..1023 float4s
            int part = fidx >> 9;
            int rowi = (fidx >> 5) & 15;
            int col4 = fidx & 31;
            int grow = part ? (DIMH + c * 16 + rowi) : (c * 16 + rowi);
            *(float4*)&wt[part][rowi][col4 * 4] =
                *(const float4*)(W + (size_t)grow * DIMH + col4 * 4);
        }
        __syncthreads();
        #pragma unroll
        for (int e = 0; e < 16; ++e) {
            float cv = cbase[c * 16 + e];               // 2-addr LDS broadcast
            float4 wv = *(const float4*)&wt[half][e][d4];
            g.x = fmaf(cv, wv.x, g.x);
            g.y = fmaf(cv, wv.y, g.y);
            g.z = fmaf(cv, wv.z, g.z);
            g.w = fmaf(cv, wv.w, g.w);
        }
    }
    g.x += __shfl_xor(g.x, 32);                        // combine h-part + o-part
    g.y += __shfl_xor(g.y, 32);
    g.z += __shfl_xor(g.z, 32);
    g.w += __shfl_xor(g.w, 32);
    float4 bv = *(const float4*)(bias + d4);           // bias added once, post-combine
    g.x += bv.x; g.y += bv.y; g.z += bv.z; g.w += bv.w;

    float4 sg;
    sg.x = 1.0f / (1.0f + __expf(-g.x));
    sg.y = 1.0f / (1.0f + __expf(-g.y));
    sg.z = 1.0f / (1.0f + __expf(-g.z));
    sg.w = 1.0f / (1.0f + __expf(-g.w));

    if (half == 0) {
        float4 hf = *(const float4*)&hi_s[r][d4];
        const size_t gi = (size_t)(b * NB + i0 + r) * DIMH;
        float4 res;
        res.x = sg.x * o.x + (1.0f - sg.x) * hf.x;
        res.y = sg.y * o.y + (1.0f - sg.y) * hf.y;
        res.z = sg.z * o.z + (1.0f - sg.z) * hf.z;
        res.w = sg.w * o.w + (1.0f - sg.w) * hf.w;
        *(float4*)(out + gi + d4) = res;
    }
}

extern "C" void kernel_launch(void* const* d_in, const int* in_sizes, int n_in,
                              void* d_out, int out_size, void* d_ws, size_t ws_size,
                              hipStream_t stream)
{
    const float* hidden = (const float*)d_in[0];
    const int*   adj    = (const int*)d_in[1];
    const int*   mask   = (const int*)d_in[2];
    const float* a0     = (const float*)d_in[3];
    const float* a1     = (const float*)d_in[4];
    const float* a2     = (const float*)d_in[5];
    const float* a3     = (const float*)d_in[6];
    const float* W      = (const float*)d_in[7];
    const float* bias   = (const float*)d_in[8];
    float* out = (float*)d_out;

    const int B = in_sizes[0] / (NB * DIMH);   // 256
    dim3 grid(B * (NB / ROWS));
    la_fused<<<grid, TPB, 0, stream>>>(hidden, adj, mask, a0, a1, a2, a3, W, bias, out);
}